// Round 1
// baseline (114.352 us; speedup 1.0000x reference)
//
#include <hip/hip_runtime.h>

// QuanvolutionClassifier: quantum patch encoder folded to y = U*v per patch.
// Kernel 0 builds U (16x16) from params; kernel 1 does everything else.

#define RPB 13          // rows (batch images) per block; 13*196 = 2548 patches ~ 10 sweeps of 256
#define NPIX 784
#define NPATCH 196

__global__ void build_U_kernel(const float* __restrict__ params, float* __restrict__ U) {
    int t = threadIdx.x;
    if (t >= 16) return;
    float st[16];
#pragma unroll
    for (int i = 0; i < 16; ++i) st[i] = (i == t) ? 1.0f : 0.0f;
#pragma unroll
    for (int l = 0; l < 4; ++l) {
#pragma unroll
        for (int w = 0; w < 4; ++w) {
            float ang = 0.5f * params[l * 4 + w];
            float c = cosf(ang), s = sinf(ang);
            const int m = 8 >> w;
#pragma unroll
            for (int idx = 0; idx < 16; ++idx) {
                if (idx & m) continue;
                float a0 = st[idx], a1 = st[idx | m];
                st[idx]     = c * a0 - s * a1;
                st[idx | m] = s * a0 + c * a1;
            }
        }
        // CX(0,1): ctrl bit8, tgt bit4 -> swap halves where ctrl set
#pragma unroll
        for (int idx = 0; idx < 16; ++idx) {
            if ((idx & 8) && !(idx & 4)) { float tmp = st[idx]; st[idx] = st[idx | 4]; st[idx | 4] = tmp; }
        }
        // CX(2,3): ctrl bit2, tgt bit1
#pragma unroll
        for (int idx = 0; idx < 16; ++idx) {
            if ((idx & 2) && !(idx & 1)) { float tmp = st[idx]; st[idx] = st[idx | 1]; st[idx | 1] = tmp; }
        }
    }
#pragma unroll
    for (int s = 0; s < 16; ++s) U[s * 16 + t] = st[s];
}

__launch_bounds__(256)
__global__ void quanv_kernel(const float* __restrict__ x,
                             const float* __restrict__ W,
                             const float* __restrict__ bias,
                             const float* __restrict__ U,
                             float* __restrict__ out,
                             int n_rows) {
    __shared__ __align__(16) float feat[RPB * NPIX];   // 40768 B -> 3 blocks/CU
    const int tid = threadIdx.x;
    const int row0 = blockIdx.x * RPB;

    // ---------------- phase 1: per-patch quantum features ----------------
    for (int g = tid; g < RPB * NPATCH; g += 256) {
        int r = g / NPATCH;                 // local row in block
        int P = g - r * NPATCH;             // patch id 0..195
        int grow = row0 + r;
        float e0 = 0.f, e1 = 0.f, e2 = 0.f, e3 = 0.f;
        if (grow < n_rows) {
            int Pr = P / 14;
            int Pc = P - Pr * 14;
            const float* px = x + (size_t)grow * NPIX + Pr * 56 + Pc * 2;
            float2 t01 = *(const float2*)px;          // pixels (2R,2C),(2R,2C+1)
            float2 t23 = *(const float2*)(px + 28);   // pixels (2R+1,2C),(2R+1,2C+1)

            float c0 = __cosf(0.5f * t01.x), s0 = __sinf(0.5f * t01.x);
            float c1 = __cosf(0.5f * t01.y), s1 = __sinf(0.5f * t01.y);
            float c2 = __cosf(0.5f * t23.x), s2 = __sinf(0.5f * t23.x);
            float c3 = __cosf(0.5f * t23.y), s3 = __sinf(0.5f * t23.y);

            float pa[4] = { c0 * c1, c0 * s1, s0 * c1, s0 * s1 };
            float pb[4] = { c2 * c3, c2 * s3, s2 * c3, s2 * s3 };
            float v[16];
#pragma unroll
            for (int a = 0; a < 4; ++a)
#pragma unroll
                for (int b2 = 0; b2 < 4; ++b2)
                    v[a * 4 + b2] = pa[a] * pb[b2];

            // y = U v ; U reads are wave-uniform -> scalar loads (SGPR FMA operands)
            float q[16];
#pragma unroll
            for (int s = 0; s < 16; ++s) {
                float acc = 0.f;
#pragma unroll
                for (int t2 = 0; t2 < 16; ++t2)
                    acc = fmaf(U[s * 16 + t2], v[t2], acc);
                q[s] = acc * acc;
            }

            // signed sums (PauliZ expectations), hierarchical (±1 Walsh slice)
            float p0 = q[0] + q[1],   m0 = q[0] - q[1];
            float p1 = q[2] + q[3],   m1 = q[2] - q[3];
            float p2 = q[4] + q[5],   m2 = q[4] - q[5];
            float p3 = q[6] + q[7],   m3 = q[6] - q[7];
            float p4 = q[8] + q[9],   m4 = q[8] - q[9];
            float p5 = q[10] + q[11], m5 = q[10] - q[11];
            float p6 = q[12] + q[13], m6 = q[12] - q[13];
            float p7 = q[14] + q[15], m7 = q[14] - q[15];
            e3 = ((m0 + m1) + (m2 + m3)) + ((m4 + m5) + (m6 + m7));
            float P0 = p0 + p1, M0 = p0 - p1;
            float P1 = p2 + p3, M1 = p2 - p3;
            float P2 = p4 + p5, M2 = p4 - p5;
            float P3 = p6 + p7, M3 = p6 - p7;
            e2 = (M0 + M1) + (M2 + M3);
            e1 = (P0 - P1) + (P2 - P3);
            e0 = (P0 + P1) - (P2 + P3);
        }
        *(float4*)&feat[r * NPIX + 4 * P] = make_float4(e0, e1, e2, e3);
    }
    __syncthreads();

    // ---------------- phase 2: feat @ W^T + b, log_softmax ----------------
    const int wid = tid >> 6, lane = tid & 63;
    for (int r = wid; r < RPB; r += 4) {
        int grow = row0 + r;
        if (grow >= n_rows) break;
        float acc[10];
#pragma unroll
        for (int o = 0; o < 10; ++o) acc[o] = 0.f;
        const float* frow = &feat[r * NPIX];
        for (int k = lane; k < NPIX; k += 64) {
            float f = frow[k];
#pragma unroll
            for (int o = 0; o < 10; ++o)
                acc[o] = fmaf(f, W[o * NPIX + k], acc[o]);
        }
#pragma unroll
        for (int o = 0; o < 10; ++o) {
            acc[o] += __shfl_xor(acc[o], 32, 64);
            acc[o] += __shfl_xor(acc[o], 16, 64);
            acc[o] += __shfl_xor(acc[o], 8, 64);
            acc[o] += __shfl_xor(acc[o], 4, 64);
            acc[o] += __shfl_xor(acc[o], 2, 64);
            acc[o] += __shfl_xor(acc[o], 1, 64);
        }
        if (lane == 0) {
            float lg[10], mx = -1e30f;
#pragma unroll
            for (int o = 0; o < 10; ++o) { lg[o] = acc[o] + bias[o]; mx = fmaxf(mx, lg[o]); }
            float sum = 0.f;
#pragma unroll
            for (int o = 0; o < 10; ++o) sum += __expf(lg[o] - mx);
            float lse = mx + __logf(sum);
#pragma unroll
            for (int o = 0; o < 10; ++o) out[(size_t)grow * 10 + o] = lg[o] - lse;
        }
    }
}

extern "C" void kernel_launch(void* const* d_in, const int* in_sizes, int n_in,
                              void* d_out, int out_size, void* d_ws, size_t ws_size,
                              hipStream_t stream) {
    const float* x      = (const float*)d_in[0];
    const float* params = (const float*)d_in[1];
    const float* W      = (const float*)d_in[2];
    const float* b      = (const float*)d_in[3];
    float* out = (float*)d_out;
    float* U   = (float*)d_ws;   // 256 floats

    int n_rows = in_sizes[0] / NPIX;   // 8192

    hipLaunchKernelGGL(build_U_kernel, dim3(1), dim3(64), 0, stream, params, U);
    int nblocks = (n_rows + RPB - 1) / RPB;
    hipLaunchKernelGGL(quanv_kernel, dim3(nblocks), dim3(256), 0, stream,
                       x, W, b, U, out, n_rows);
}

// Round 2
// 98.794 us; speedup vs baseline: 1.1575x; 1.1575x over previous
//
#include <hip/hip_runtime.h>

// QuanvolutionClassifier: quantum patch encoder folded to y = U*v per patch.
// Kernel 0 builds U (16x16) from params; kernel 1 does everything else.
//
// R2: RPB 13->4 (LDS 40KB->12.5KB, grid 631->2048) to go from 2.46 blocks/CU
// (17.8% occupancy, latency-bound) to 8 blocks/CU * 4 waves = 32 waves/CU.
// Wave-granular tail: 784 tasks / 256 threads -> wave0 does 4 iters, waves1-3
// do 3 (94.2% wave-level utilization).

#define RPB 4           // rows (batch images) per block
#define NPIX 784
#define NPATCH 196

__global__ void build_U_kernel(const float* __restrict__ params, float* __restrict__ U) {
    int t = threadIdx.x;
    if (t >= 16) return;
    float st[16];
#pragma unroll
    for (int i = 0; i < 16; ++i) st[i] = (i == t) ? 1.0f : 0.0f;
#pragma unroll
    for (int l = 0; l < 4; ++l) {
#pragma unroll
        for (int w = 0; w < 4; ++w) {
            float ang = 0.5f * params[l * 4 + w];
            float c = cosf(ang), s = sinf(ang);
            const int m = 8 >> w;
#pragma unroll
            for (int idx = 0; idx < 16; ++idx) {
                if (idx & m) continue;
                float a0 = st[idx], a1 = st[idx | m];
                st[idx]     = c * a0 - s * a1;
                st[idx | m] = s * a0 + c * a1;
            }
        }
        // CX(0,1): ctrl bit8, tgt bit4 -> swap halves where ctrl set
#pragma unroll
        for (int idx = 0; idx < 16; ++idx) {
            if ((idx & 8) && !(idx & 4)) { float tmp = st[idx]; st[idx] = st[idx | 4]; st[idx | 4] = tmp; }
        }
        // CX(2,3): ctrl bit2, tgt bit1
#pragma unroll
        for (int idx = 0; idx < 16; ++idx) {
            if ((idx & 2) && !(idx & 1)) { float tmp = st[idx]; st[idx] = st[idx | 1]; st[idx | 1] = tmp; }
        }
    }
#pragma unroll
    for (int s = 0; s < 16; ++s) U[s * 16 + t] = st[s];
}

__launch_bounds__(256, 8)   // 8 waves/EU -> caps VGPR<=64, 8 blocks/CU, 32 waves/CU
__global__ void quanv_kernel(const float* __restrict__ x,
                             const float* __restrict__ W,
                             const float* __restrict__ bias,
                             const float* __restrict__ U,
                             float* __restrict__ out,
                             int n_rows) {
    __shared__ __align__(16) float feat[RPB * NPIX];   // 12544 B
    const int tid = threadIdx.x;
    const int row0 = blockIdx.x * RPB;

    // ---------------- phase 1: per-patch quantum features ----------------
    for (int g = tid; g < RPB * NPATCH; g += 256) {
        int r = g / NPATCH;                 // local row in block
        int P = g - r * NPATCH;             // patch id 0..195
        int grow = row0 + r;
        float e0 = 0.f, e1 = 0.f, e2 = 0.f, e3 = 0.f;
        if (grow < n_rows) {
            int Pr = P / 14;
            int Pc = P - Pr * 14;
            const float* px = x + (size_t)grow * NPIX + Pr * 56 + Pc * 2;
            float2 t01 = *(const float2*)px;          // pixels (2R,2C),(2R,2C+1)
            float2 t23 = *(const float2*)(px + 28);   // pixels (2R+1,2C),(2R+1,2C+1)

            float c0 = __cosf(0.5f * t01.x), s0 = __sinf(0.5f * t01.x);
            float c1 = __cosf(0.5f * t01.y), s1 = __sinf(0.5f * t01.y);
            float c2 = __cosf(0.5f * t23.x), s2 = __sinf(0.5f * t23.x);
            float c3 = __cosf(0.5f * t23.y), s3 = __sinf(0.5f * t23.y);

            float pa[4] = { c0 * c1, c0 * s1, s0 * c1, s0 * s1 };
            float pb[4] = { c2 * c3, c2 * s3, s2 * c3, s2 * s3 };
            float v[16];
#pragma unroll
            for (int a = 0; a < 4; ++a)
#pragma unroll
                for (int b2 = 0; b2 < 4; ++b2)
                    v[a * 4 + b2] = pa[a] * pb[b2];

            // y = U v ; U reads are wave-uniform -> scalar loads (SGPR FMA operands)
            float q[16];
#pragma unroll
            for (int s = 0; s < 16; ++s) {
                float acc = 0.f;
#pragma unroll
                for (int t2 = 0; t2 < 16; ++t2)
                    acc = fmaf(U[s * 16 + t2], v[t2], acc);
                q[s] = acc * acc;
            }

            // signed sums (PauliZ expectations), hierarchical (±1 Walsh slice)
            float p0 = q[0] + q[1],   m0 = q[0] - q[1];
            float p1 = q[2] + q[3],   m1 = q[2] - q[3];
            float p2 = q[4] + q[5],   m2 = q[4] - q[5];
            float p3 = q[6] + q[7],   m3 = q[6] - q[7];
            float p4 = q[8] + q[9],   m4 = q[8] - q[9];
            float p5 = q[10] + q[11], m5 = q[10] - q[11];
            float p6 = q[12] + q[13], m6 = q[12] - q[13];
            float p7 = q[14] + q[15], m7 = q[14] - q[15];
            e3 = ((m0 + m1) + (m2 + m3)) + ((m4 + m5) + (m6 + m7));
            float P0 = p0 + p1, M0 = p0 - p1;
            float P1 = p2 + p3, M1 = p2 - p3;
            float P2 = p4 + p5, M2 = p4 - p5;
            float P3 = p6 + p7, M3 = p6 - p7;
            e2 = (M0 + M1) + (M2 + M3);
            e1 = (P0 - P1) + (P2 - P3);
            e0 = (P0 + P1) - (P2 + P3);
        }
        *(float4*)&feat[r * NPIX + 4 * P] = make_float4(e0, e1, e2, e3);
    }
    __syncthreads();

    // ---------------- phase 2: feat @ W^T + b, log_softmax ----------------
    const int wid = tid >> 6, lane = tid & 63;
    for (int r = wid; r < RPB; r += 4) {
        int grow = row0 + r;
        if (grow >= n_rows) break;
        float acc[10];
#pragma unroll
        for (int o = 0; o < 10; ++o) acc[o] = 0.f;
        const float* frow = &feat[r * NPIX];
        for (int k = lane; k < NPIX; k += 64) {
            float f = frow[k];
#pragma unroll
            for (int o = 0; o < 10; ++o)
                acc[o] = fmaf(f, W[o * NPIX + k], acc[o]);
        }
#pragma unroll
        for (int o = 0; o < 10; ++o) {
            acc[o] += __shfl_xor(acc[o], 32, 64);
            acc[o] += __shfl_xor(acc[o], 16, 64);
            acc[o] += __shfl_xor(acc[o], 8, 64);
            acc[o] += __shfl_xor(acc[o], 4, 64);
            acc[o] += __shfl_xor(acc[o], 2, 64);
            acc[o] += __shfl_xor(acc[o], 1, 64);
        }
        if (lane == 0) {
            float lg[10], mx = -1e30f;
#pragma unroll
            for (int o = 0; o < 10; ++o) { lg[o] = acc[o] + bias[o]; mx = fmaxf(mx, lg[o]); }
            float sum = 0.f;
#pragma unroll
            for (int o = 0; o < 10; ++o) sum += __expf(lg[o] - mx);
            float lse = mx + __logf(sum);
#pragma unroll
            for (int o = 0; o < 10; ++o) out[(size_t)grow * 10 + o] = lg[o] - lse;
        }
    }
}

extern "C" void kernel_launch(void* const* d_in, const int* in_sizes, int n_in,
                              void* d_out, int out_size, void* d_ws, size_t ws_size,
                              hipStream_t stream) {
    const float* x      = (const float*)d_in[0];
    const float* params = (const float*)d_in[1];
    const float* W      = (const float*)d_in[2];
    const float* b      = (const float*)d_in[3];
    float* out = (float*)d_out;
    float* U   = (float*)d_ws;   // 256 floats

    int n_rows = in_sizes[0] / NPIX;   // 8192

    hipLaunchKernelGGL(build_U_kernel, dim3(1), dim3(64), 0, stream, params, U);
    int nblocks = (n_rows + RPB - 1) / RPB;
    hipLaunchKernelGGL(quanv_kernel, dim3(nblocks), dim3(256), 0, stream,
                       x, W, b, U, out, n_rows);
}

// Round 3
// 87.511 us; speedup vs baseline: 1.3067x; 1.1289x over previous
//
#include <hip/hip_runtime.h>

// QuanvolutionClassifier.
// R3 key insight: the circuit's only entanglers are CX(0,1) and CX(2,3) —
// wire pairs {0,1} and {2,3} NEVER couple. So the 16x16 ansatz operator
// factorizes exactly: U = U01 (x) U23 (two 4x4s), and with the product-state
// encoder v = pa (x) pb:
//     y = (U01 pa) (x) (U23 pb)          -> 2 x (4x4 matvec) = 32 FMA/patch
//     sum_b (U23 pb)_b^2 = 1             -> wire-0/1 expectations from ya^2
//     sum_a (U01 pa)_a^2 = 1             -> wire-2/3 expectations from yb^2
// Phase-1 VALU drops ~5x vs the dense 16x16 matvec. 32 U coeffs live in SGPRs
// (wave-uniform, hoisted out of the patch loop).

#define RPB 4           // rows (batch images) per block
#define NPIX 784
#define NPATCH 196

// U[0..15] = U01 row-major, U[16..31] = U23 row-major.
__global__ void build_U_kernel(const float* __restrict__ params, float* __restrict__ U) {
    int t = threadIdx.x;
    if (t >= 8) return;
    int pair = t >> 2;        // 0 -> wires {0,1}, 1 -> wires {2,3}
    int col  = t & 3;         // basis column
    float st[4];
#pragma unroll
    for (int i = 0; i < 4; ++i) st[i] = (i == col) ? 1.0f : 0.0f;
#pragma unroll
    for (int l = 0; l < 4; ++l) {
        float ah = 0.5f * params[l * 4 + pair * 2 + 0];   // high bit (wire pair*2)
        float al = 0.5f * params[l * 4 + pair * 2 + 1];   // low bit  (wire pair*2+1)
        float ch = cosf(ah), sh = sinf(ah);
        // RY on high bit: pairs (0,2),(1,3)
#pragma unroll
        for (int j = 0; j < 2; ++j) {
            float u = st[j], w = st[j + 2];
            st[j]     = ch * u - sh * w;
            st[j + 2] = sh * u + ch * w;
        }
        float cl = cosf(al), sl = sinf(al);
        // RY on low bit: pairs (0,1),(2,3)
#pragma unroll
        for (int j = 0; j < 4; j += 2) {
            float u = st[j], w = st[j + 1];
            st[j]     = cl * u - sl * w;
            st[j + 1] = sl * u + cl * w;
        }
        // CX(high->low): swap states 2,3
        float tmp = st[2]; st[2] = st[3]; st[3] = tmp;
    }
#pragma unroll
    for (int s = 0; s < 4; ++s) U[pair * 16 + s * 4 + col] = st[s];
}

__launch_bounds__(256, 8)   // 8 waves/EU -> VGPR<=64, 8 blocks/CU, 32 waves/CU
__global__ void quanv_kernel(const float* __restrict__ x,
                             const float* __restrict__ W,
                             const float* __restrict__ bias,
                             const float* __restrict__ U,
                             float* __restrict__ out,
                             int n_rows) {
    __shared__ __align__(16) float feat[RPB * NPIX];   // 12544 B
    const int tid = threadIdx.x;
    const int row0 = blockIdx.x * RPB;

    // 32 wave-uniform coeffs -> SGPRs, hoisted out of the patch loop
    float Ua[16], Ub[16];
#pragma unroll
    for (int i = 0; i < 16; ++i) { Ua[i] = U[i]; Ub[i] = U[16 + i]; }

    // ---------------- phase 1: per-patch quantum features ----------------
    for (int g = tid; g < RPB * NPATCH; g += 256) {
        int r = g / NPATCH;                 // local row in block
        int P = g - r * NPATCH;             // patch id 0..195
        int grow = row0 + r;
        float e0 = 0.f, e1 = 0.f, e2 = 0.f, e3 = 0.f;
        if (grow < n_rows) {
            int Pr = P / 14;
            int Pc = P - Pr * 14;
            const float* px = x + (size_t)grow * NPIX + Pr * 56 + Pc * 2;
            float2 t01 = *(const float2*)px;          // pixels (2R,2C),(2R,2C+1)
            float2 t23 = *(const float2*)(px + 28);   // pixels (2R+1,2C),(2R+1,2C+1)

            float c0 = __cosf(0.5f * t01.x), s0 = __sinf(0.5f * t01.x);
            float c1 = __cosf(0.5f * t01.y), s1 = __sinf(0.5f * t01.y);
            float c2 = __cosf(0.5f * t23.x), s2 = __sinf(0.5f * t23.x);
            float c3 = __cosf(0.5f * t23.y), s3 = __sinf(0.5f * t23.y);

            float pa[4] = { c0 * c1, c0 * s1, s0 * c1, s0 * s1 };
            float pb[4] = { c2 * c3, c2 * s3, s2 * c3, s2 * s3 };

            float qa[4], qb[4];
#pragma unroll
            for (int s = 0; s < 4; ++s) {
                float ya = fmaf(Ua[s * 4 + 3], pa[3],
                           fmaf(Ua[s * 4 + 2], pa[2],
                           fmaf(Ua[s * 4 + 1], pa[1], Ua[s * 4 + 0] * pa[0])));
                float yb = fmaf(Ub[s * 4 + 3], pb[3],
                           fmaf(Ub[s * 4 + 2], pb[2],
                           fmaf(Ub[s * 4 + 1], pb[1], Ub[s * 4 + 0] * pb[0])));
                qa[s] = ya * ya;
                qb[s] = yb * yb;
            }
            // Z expectations: wire0/1 from qa (|yb|^2=1), wire2/3 from qb
            e0 = (qa[0] + qa[1]) - (qa[2] + qa[3]);
            e1 = (qa[0] - qa[1]) + (qa[2] - qa[3]);
            e2 = (qb[0] + qb[1]) - (qb[2] + qb[3]);
            e3 = (qb[0] - qb[1]) + (qb[2] - qb[3]);
        }
        *(float4*)&feat[r * NPIX + 4 * P] = make_float4(e0, e1, e2, e3);
    }
    __syncthreads();

    // ---------------- phase 2: feat @ W^T + b, log_softmax ----------------
    const int wid = tid >> 6, lane = tid & 63;
    const float4* W4 = (const float4*)W;               // W4[o*196 + k]
    for (int r = wid; r < RPB; r += 4) {
        int grow = row0 + r;
        if (grow >= n_rows) break;
        float acc[10];
#pragma unroll
        for (int o = 0; o < 10; ++o) acc[o] = 0.f;
        const float4* frow4 = (const float4*)&feat[r * NPIX];   // 196 float4
        for (int k = lane; k < NPATCH; k += 64) {
            float4 f = frow4[k];
#pragma unroll
            for (int o = 0; o < 10; ++o) {
                float4 w = W4[o * NPATCH + k];
                acc[o] = fmaf(f.x, w.x, fmaf(f.y, w.y, fmaf(f.z, w.z, fmaf(f.w, w.w, acc[o]))));
            }
        }
#pragma unroll
        for (int o = 0; o < 10; ++o) {
            acc[o] += __shfl_xor(acc[o], 32, 64);
            acc[o] += __shfl_xor(acc[o], 16, 64);
            acc[o] += __shfl_xor(acc[o], 8, 64);
            acc[o] += __shfl_xor(acc[o], 4, 64);
            acc[o] += __shfl_xor(acc[o], 2, 64);
            acc[o] += __shfl_xor(acc[o], 1, 64);
        }
        if (lane == 0) {
            float lg[10], mx = -1e30f;
#pragma unroll
            for (int o = 0; o < 10; ++o) { lg[o] = acc[o] + bias[o]; mx = fmaxf(mx, lg[o]); }
            float sum = 0.f;
#pragma unroll
            for (int o = 0; o < 10; ++o) sum += __expf(lg[o] - mx);
            float lse = mx + __logf(sum);
#pragma unroll
            for (int o = 0; o < 10; ++o) out[(size_t)grow * 10 + o] = lg[o] - lse;
        }
    }
}

extern "C" void kernel_launch(void* const* d_in, const int* in_sizes, int n_in,
                              void* d_out, int out_size, void* d_ws, size_t ws_size,
                              hipStream_t stream) {
    const float* x      = (const float*)d_in[0];
    const float* params = (const float*)d_in[1];
    const float* W      = (const float*)d_in[2];
    const float* b      = (const float*)d_in[3];
    float* out = (float*)d_out;
    float* U   = (float*)d_ws;   // 32 floats: U01 then U23

    int n_rows = in_sizes[0] / NPIX;   // 8192

    hipLaunchKernelGGL(build_U_kernel, dim3(1), dim3(64), 0, stream, params, U);
    int nblocks = (n_rows + RPB - 1) / RPB;
    hipLaunchKernelGGL(quanv_kernel, dim3(nblocks), dim3(256), 0, stream,
                       x, W, b, U, out, n_rows);
}

// Round 4
// 85.965 us; speedup vs baseline: 1.3302x; 1.0180x over previous
//
#include <hip/hip_runtime.h>

// QuanvolutionClassifier — fully fused single kernel.
// R3: U = U01 (x) U23 factorization (CX(0,1), CX(2,3) never couple pairs).
// R4: fuse build_U into the main kernel. Each block rebuilds the two 4x4
// ansatz matrices with 8 lanes (~100 FLOPs), stages in LDS, then every
// thread pins the 32 coeffs into SGPRs via readfirstlane — the per-patch
// matvec reads zero per-lane memory operands. One launch, no d_ws.

#define RPB 4           // rows (batch images) per block
#define NPIX 784
#define NPATCH 196

__device__ __forceinline__ float rfl(float v) {
    return __uint_as_float(__builtin_amdgcn_readfirstlane(__float_as_uint(v)));
}

__launch_bounds__(256, 8)   // 8 waves/EU -> VGPR<=64, 8 blocks/CU, 32 waves/CU
__global__ void quanv_kernel(const float* __restrict__ x,
                             const float* __restrict__ params,
                             const float* __restrict__ W,
                             const float* __restrict__ bias,
                             float* __restrict__ out,
                             int n_rows) {
    __shared__ __align__(16) float feat[RPB * NPIX];   // 12544 B
    __shared__ float Ush[32];                          // U01 | U23
    const int tid = threadIdx.x;
    const int row0 = blockIdx.x * RPB;

    // ---- build U01/U23 (8 lanes, ~100 FLOPs, redundant per block) ----
    if (tid < 8) {
        int pair = tid >> 2;      // 0 -> wires {0,1}, 1 -> wires {2,3}
        int col  = tid & 3;       // basis column
        float st[4];
#pragma unroll
        for (int i = 0; i < 4; ++i) st[i] = (i == col) ? 1.0f : 0.0f;
#pragma unroll
        for (int l = 0; l < 4; ++l) {
            float ah = 0.5f * params[l * 4 + pair * 2 + 0];   // high wire of pair
            float al = 0.5f * params[l * 4 + pair * 2 + 1];   // low wire of pair
            float ch = cosf(ah), sh = sinf(ah);
#pragma unroll
            for (int j = 0; j < 2; ++j) {                     // RY on high bit
                float u = st[j], w = st[j + 2];
                st[j]     = ch * u - sh * w;
                st[j + 2] = sh * u + ch * w;
            }
            float cl = cosf(al), sl = sinf(al);
#pragma unroll
            for (int j = 0; j < 4; j += 2) {                  // RY on low bit
                float u = st[j], w = st[j + 1];
                st[j]     = cl * u - sl * w;
                st[j + 1] = sl * u + cl * w;
            }
            float tmp = st[2]; st[2] = st[3]; st[3] = tmp;    // CX: swap |10>,|11>
        }
#pragma unroll
        for (int s = 0; s < 4; ++s) Ush[pair * 16 + s * 4 + col] = st[s];
    }
    __syncthreads();

    // pin the 32 wave-uniform coeffs into SGPRs
    float Ua[16], Ub[16];
#pragma unroll
    for (int i = 0; i < 16; ++i) { Ua[i] = rfl(Ush[i]); Ub[i] = rfl(Ush[16 + i]); }

    // ---------------- phase 1: per-patch quantum features ----------------
    for (int g = tid; g < RPB * NPATCH; g += 256) {
        int r = g / NPATCH;                 // local row in block
        int P = g - r * NPATCH;             // patch id 0..195
        int grow = row0 + r;
        float e0 = 0.f, e1 = 0.f, e2 = 0.f, e3 = 0.f;
        if (grow < n_rows) {
            int Pr = P / 14;
            int Pc = P - Pr * 14;
            const float* px = x + (size_t)grow * NPIX + Pr * 56 + Pc * 2;
            float2 t01 = *(const float2*)px;          // pixels (2R,2C),(2R,2C+1)
            float2 t23 = *(const float2*)(px + 28);   // pixels (2R+1,2C),(2R+1,2C+1)

            float c0 = __cosf(0.5f * t01.x), s0 = __sinf(0.5f * t01.x);
            float c1 = __cosf(0.5f * t01.y), s1 = __sinf(0.5f * t01.y);
            float c2 = __cosf(0.5f * t23.x), s2 = __sinf(0.5f * t23.x);
            float c3 = __cosf(0.5f * t23.y), s3 = __sinf(0.5f * t23.y);

            float pa[4] = { c0 * c1, c0 * s1, s0 * c1, s0 * s1 };
            float pb[4] = { c2 * c3, c2 * s3, s2 * c3, s2 * s3 };

            float qa[4], qb[4];
#pragma unroll
            for (int s = 0; s < 4; ++s) {
                float ya = fmaf(Ua[s * 4 + 3], pa[3],
                           fmaf(Ua[s * 4 + 2], pa[2],
                           fmaf(Ua[s * 4 + 1], pa[1], Ua[s * 4 + 0] * pa[0])));
                float yb = fmaf(Ub[s * 4 + 3], pb[3],
                           fmaf(Ub[s * 4 + 2], pb[2],
                           fmaf(Ub[s * 4 + 1], pb[1], Ub[s * 4 + 0] * pb[0])));
                qa[s] = ya * ya;
                qb[s] = yb * yb;
            }
            // Z expectations: wire0/1 from qa (|yb|^2=1), wire2/3 from qb
            e0 = (qa[0] + qa[1]) - (qa[2] + qa[3]);
            e1 = (qa[0] - qa[1]) + (qa[2] - qa[3]);
            e2 = (qb[0] + qb[1]) - (qb[2] + qb[3]);
            e3 = (qb[0] - qb[1]) + (qb[2] - qb[3]);
        }
        *(float4*)&feat[r * NPIX + 4 * P] = make_float4(e0, e1, e2, e3);
    }
    __syncthreads();

    // ---------------- phase 2: feat @ W^T + b, log_softmax ----------------
    const int wid = tid >> 6, lane = tid & 63;
    const float4* W4 = (const float4*)W;               // W4[o*196 + k]
    for (int r = wid; r < RPB; r += 4) {
        int grow = row0 + r;
        if (grow >= n_rows) break;
        float acc[10];
#pragma unroll
        for (int o = 0; o < 10; ++o) acc[o] = 0.f;
        const float4* frow4 = (const float4*)&feat[r * NPIX];   // 196 float4
        for (int k = lane; k < NPATCH; k += 64) {
            float4 f = frow4[k];
#pragma unroll
            for (int o = 0; o < 10; ++o) {
                float4 w = W4[o * NPATCH + k];
                acc[o] = fmaf(f.x, w.x, fmaf(f.y, w.y, fmaf(f.z, w.z, fmaf(f.w, w.w, acc[o]))));
            }
        }
#pragma unroll
        for (int o = 0; o < 10; ++o) {
            acc[o] += __shfl_xor(acc[o], 32, 64);
            acc[o] += __shfl_xor(acc[o], 16, 64);
            acc[o] += __shfl_xor(acc[o], 8, 64);
            acc[o] += __shfl_xor(acc[o], 4, 64);
            acc[o] += __shfl_xor(acc[o], 2, 64);
            acc[o] += __shfl_xor(acc[o], 1, 64);
        }
        if (lane == 0) {
            float lg[10], mx = -1e30f;
#pragma unroll
            for (int o = 0; o < 10; ++o) { lg[o] = acc[o] + bias[o]; mx = fmaxf(mx, lg[o]); }
            float sum = 0.f;
#pragma unroll
            for (int o = 0; o < 10; ++o) sum += __expf(lg[o] - mx);
            float lse = mx + __logf(sum);
#pragma unroll
            for (int o = 0; o < 10; ++o) out[(size_t)grow * 10 + o] = lg[o] - lse;
        }
    }
}

extern "C" void kernel_launch(void* const* d_in, const int* in_sizes, int n_in,
                              void* d_out, int out_size, void* d_ws, size_t ws_size,
                              hipStream_t stream) {
    const float* x      = (const float*)d_in[0];
    const float* params = (const float*)d_in[1];
    const float* W      = (const float*)d_in[2];
    const float* b      = (const float*)d_in[3];
    float* out = (float*)d_out;

    int n_rows = in_sizes[0] / NPIX;   // 8192
    int nblocks = (n_rows + RPB - 1) / RPB;
    hipLaunchKernelGGL(quanv_kernel, dim3(nblocks), dim3(256), 0, stream,
                       x, params, W, b, out, n_rows);
}